// Round 16
// baseline (110.806 us; speedup 1.0000x reference)
//
#include <hip/hip_runtime.h>
#include <cstdint>

typedef __attribute__((ext_vector_type(8)))  short short8;
typedef __attribute__((ext_vector_type(16))) float floatx16;

constexpr int NB = 4;        // batch
constexpr int NV = 8192;     // vertices
constexpr int NF = 16384;    // faces
constexpr int NP = 8192;     // query points per batch
constexpr float F_EPS = 1e-3f;
constexpr float F_WEIGHT = 1000.0f;
constexpr float BIAS = 1e-3f;        // keeps dist^2 > 0 despite bf16 rounding

constexpr int PT_TILES = NP / 32;        // 256 point tiles (32-wide) / batch
constexpr int FC_TILES = NF / 32;        // 512 face tiles (32-wide) / batch
constexpr int TPB = 256;                 // 4 waves
constexpr int FS = 16;                   // face slices
constexpr int SL_TILES = FC_TILES / FS;  // 32 face tiles (1024 faces) / slice -> 32KB LDS
constexpr int GPW = 4;                   // point-tile iterations per wave
constexpr int PGB = 16;                  // point groups (512 pts) / batch
// grid = PGB x FS x NB = 1024 blocks = 4/CU, fully co-resident

union FragU { uint4 u; short8 s; };

__device__ inline unsigned f2bf(float f) {           // fp32 -> bf16 (RNE)
    unsigned u = __float_as_uint(f);
    return (u + 0x7FFFu + ((u >> 16) & 1u)) >> 16;
}
__device__ inline float bf2f(unsigned h) { return __uint_as_float(h << 16); }
__device__ inline unsigned pk(unsigned lo, unsigned hi) {
    return (lo & 0xFFFFu) | (hi << 16);
}

// ---------------------------------------------------------------------------
// Fused prep (unchanged; verified absmax 0.0 through r6-r15).
// ---------------------------------------------------------------------------
__global__ void prep_kernel(const float* __restrict__ pred,
                            const float* __restrict__ pos,
                            const int*   __restrict__ faces,
                            uint4* __restrict__ a_frags,
                            uint4* __restrict__ b_frags,
                            float4* __restrict__ centers4,
                            float4* __restrict__ normals4,
                            unsigned* __restrict__ keys,
                            float* __restrict__ acc,
                            unsigned* __restrict__ tk) {
    int i = blockIdx.x * blockDim.x + threadIdx.x;   // [0, NB*NF)
    if (i >= NB * NF) return;
    if (i < 2) acc[i] = 0.0f;
    if (i == 0) tk[0] = 0u;

    const unsigned ONE = 0x3F80u;

    // ---- faces ----
    {
        int b = i / NF, f = i & (NF - 1);
        const float* p = pos + (size_t)b * NV * 3;
        int i0 = faces[3 * (size_t)i], i1 = faces[3 * (size_t)i + 1], i2 = faces[3 * (size_t)i + 2];
        float ax = p[3 * i0], ay = p[3 * i0 + 1], az = p[3 * i0 + 2];
        float bx = p[3 * i1], by = p[3 * i1 + 1], bz = p[3 * i1 + 2];
        float cx = p[3 * i2], cy = p[3 * i2 + 1], cz = p[3 * i2 + 2];

        const float third = 1.0f / 3.0f;
        float mx = (ax + bx + cx) * third;
        float my = (ay + by + cy) * third;
        float mz = (az + bz + cz) * third;
        float c2 = mx * mx + my * my + mz * mz;

        float e1x = bx - ax, e1y = by - ay, e1z = bz - az;
        float e2x = cx - ax, e2y = cy - ay, e2z = cz - az;
        float nx = e1y * e2z - e1z * e2y;
        float ny = e1z * e2x - e1x * e2z;
        float nz = e1x * e2y - e1y * e2x;
        float len = sqrtf(nx * nx + ny * ny + nz * nz);
        float inv = 1.0f / fmaxf(len, 1e-12f);

        centers4[i] = make_float4(mx, my, mz, c2);
        normals4[i] = make_float4(nx * inv, ny * inv, nz * inv, 0.0f);

        unsigned bhx = f2bf(mx), bhy = f2bf(my), bhz = f2bf(mz);
        unsigned blx = f2bf(mx - bf2f(bhx)), bly = f2bf(my - bf2f(bhy)), blz = f2bf(mz - bf2f(bhz));
        unsigned c2h = f2bf(c2);
        unsigned c2l = f2bf(c2 - bf2f(c2h));

        int tile = f >> 5, n = f & 31;
        uint4* bb = b_frags + (size_t)(b * FC_TILES + tile) * 64;
        bb[n]      = make_uint4(pk(bhx, bhy), pk(bhz, bhx), pk(bhy, bhz), pk(blx, bly)); // k0..7
        bb[32 + n] = make_uint4(pk(blz, blx), pk(bly, blz), pk(c2h, c2l), pk(ONE, ONE)); // k8..15
    }

    // ---- points ----
    if (i < NB * NP) {
        keys[i] = 0xFFFFFFFFu;
        int pb = i / NP, pn = i & (NP - 1);
        float x = pred[3 * (size_t)i], y = pred[3 * (size_t)i + 1], z = pred[3 * (size_t)i + 2];
        unsigned hx = f2bf(x), hy = f2bf(y), hz = f2bf(z);
        float rx = x - bf2f(hx), ry = y - bf2f(hy), rz = z - bf2f(hz);
        unsigned ahx = f2bf(-2.f * bf2f(hx)), ahy = f2bf(-2.f * bf2f(hy)), ahz = f2bf(-2.f * bf2f(hz));
        unsigned alx = f2bf(-2.f * rx), aly = f2bf(-2.f * ry), alz = f2bf(-2.f * rz);
        float p2 = x * x + y * y + z * z + BIAS;
        unsigned p2h = f2bf(p2);
        unsigned p2l = f2bf(p2 - bf2f(p2h));

        int tile = pn >> 5, m = pn & 31;
        uint4* ab = a_frags + (size_t)(pb * PT_TILES + tile) * 64;
        ab[m]      = make_uint4(pk(ahx, ahy), pk(ahz, alx), pk(aly, alz), pk(ahx, ahy)); // k0..7
        ab[32 + m] = make_uint4(pk(ahz, alx), pk(aly, alz), pk(ONE, ONE), pk(p2h, p2l)); // k8..15
    }
}

// One epilogue triple: k0=(D0&mask)|vf ; k1=(D1&mask)|vf32 ; best=min3
#define EP(D0, D1, BB) \
    "v_and_or_b32 v64, " D0 ", %[m], v66\n\t" \
    "v_and_or_b32 v65, " D1 ", %[m], v67\n\t" \
    "v_min3_u32 " BB ", " BB ", v64, v65\n\t"

#define EPILOGUE \
    "v_add_u32 v67, 32, v66\n\t" \
    "s_nop 7\n\t" \
    "s_nop 7\n\t" \
    "s_nop 7\n\t" \
    EP("v0",  "v16", "v32") EP("v1",  "v17", "v33") \
    EP("v2",  "v18", "v34") EP("v3",  "v19", "v35") \
    EP("v4",  "v20", "v36") EP("v5",  "v21", "v37") \
    EP("v6",  "v22", "v38") EP("v7",  "v23", "v39") \
    EP("v8",  "v24", "v40") EP("v9",  "v25", "v41") \
    EP("v10", "v26", "v42") EP("v11", "v27", "v43") \
    EP("v12", "v28", "v44") EP("v13", "v29", "v45") \
    EP("v14", "v30", "v46") EP("v15", "v31", "v47") \
    "v_add_u32 v66, 64, v66\n\t"

// Pair with current operands in fbA (v48-55), prefetch next pair into fbB.
#define PAIR_A(P0, P1) \
    "ds_read_b128 v[56:59], v68 offset:" P0 "\n\t" \
    "ds_read_b128 v[60:63], v68 offset:" P1 "\n\t" \
    "s_waitcnt lgkmcnt(2)\n\t" \
    "v_mfma_f32_32x32x16_bf16 v[0:15], %[fa], v[48:51], %[fz]\n\t" \
    "v_mfma_f32_32x32x16_bf16 v[16:31], %[fa], v[52:55], %[fz]\n\t" \
    EPILOGUE

// Pair with current operands in fbB (v56-63), prefetch next pair into fbA.
#define PAIR_B(P0, P1) \
    "ds_read_b128 v[48:51], v68 offset:" P0 "\n\t" \
    "ds_read_b128 v[52:55], v68 offset:" P1 "\n\t" \
    "s_waitcnt lgkmcnt(2)\n\t" \
    "v_mfma_f32_32x32x16_bf16 v[0:15], %[fa], v[56:59], %[fz]\n\t" \
    "v_mfma_f32_32x32x16_bf16 v[16:31], %[fa], v[60:63], %[fz]\n\t" \
    EPILOGUE

// Last pair (current in fbB), nothing left to prefetch.
#define PAIR_B_LAST \
    "s_waitcnt lgkmcnt(0)\n\t" \
    "v_mfma_f32_32x32x16_bf16 v[0:15], %[fa], v[56:59], %[fz]\n\t" \
    "v_mfma_f32_32x32x16_bf16 v[16:31], %[fa], v[60:63], %[fz]\n\t" \
    EPILOGUE

// ---------------------------------------------------------------------------
// 1-NN on the matrix pipe: r15 mega-asm + 4 COMPUTE ITERATIONS PER BLOCK.
// r13/r14/r15 all landed at exactly 43.5us despite prefetch/DMA/isel changes
// -> the limiter is per-block fixed cost (dispatch, A-load, staging drain,
// reduction tail, cross-XCD atomic tail: WRITE_SIZE=8MiB on a 128KiB keys
// array = atomic line ping-pong), with only 2.56 blocks/CU resident to
// overlap it (block lifetime ~16.8k cyc vs ~3k compute). This round each
// wave loops g=0..3 over four A-tiles (pt_tile = pg*16 + g*4 + wave),
// reusing one staged slice; grid = 1024 blocks = 4/CU, ALL co-resident in a
// single dispatch wave. Fixed costs amortize 4x and overlap across 16
// waves/CU. Asm block unchanged (verified absmax 0.0 r13-r15).
// key = (bits(dist^2+BIAS) & 0xFFFFC000) | face_idx; cross-slice atomicMin.
// ---------------------------------------------------------------------------
__global__ __launch_bounds__(TPB) void nn_kernel(
        const uint4* __restrict__ a_frags,
        const uint4* __restrict__ b_frags,
        unsigned* __restrict__ keys) {
    const int pg = blockIdx.x, sl = blockIdx.y, b = blockIdx.z;
    const int tid = threadIdx.x, wave = tid >> 6, lane = tid & 63;

    __shared__ uint4 sb[SL_TILES * 64];        // 32 KB

    // async DMA stage of the whole 32-tile slice (no VGPR round-trip)
    const uint4* gsrc = b_frags + ((size_t)(b * FC_TILES + sl * SL_TILES)) * 64;
#pragma unroll
    for (int k = 0; k < (SL_TILES * 64) / TPB; ++k) {
        __builtin_amdgcn_global_load_lds(
            (const __attribute__((address_space(1))) unsigned int*)(const void*)(gsrc + k * TPB + tid),
            (__attribute__((address_space(3))) unsigned int*)(void*)&sb[k * TPB + (wave << 6)],
            16, 0, 0);
    }
    __syncthreads();   // compiler emits vmcnt(0) drain before s_barrier

    const floatx16 zero = {0.f, 0.f, 0.f, 0.f, 0.f, 0.f, 0.f, 0.f,
                           0.f, 0.f, 0.f, 0.f, 0.f, 0.f, 0.f, 0.f};
    const unsigned mask = 0xFFFFC000u;
    const unsigned vf_base = (unsigned)(sl * (SL_TILES * 32) + (lane & 31));
    // shared aperture is 2^48-aligned -> low 32 bits of the flat address are
    // the LDS segment offset.
    const unsigned lds_base = (unsigned)(unsigned long long)&sb[lane];
    unsigned* kb = keys + b * NP;

    for (int g = 0; g < GPW; ++g) {
        // one 32-point A-tile per wave per iteration
        const int pt_tile = pg * 16 + g * 4 + wave;
        FragU a;
        a.u = a_frags[((size_t)(b * PT_TILES + pt_tile)) * 64 + lane];

        unsigned b0, b1, b2, b3, b4, b5, b6, b7, b8, b9, b10, b11, b12, b13, b14, b15;
        asm volatile(
            "v_mov_b32 v68, %[lb]\n\t"
            "v_mov_b32 v66, %[vfb]\n\t"
            "v_mov_b32 v32, -1\n\t" "v_mov_b32 v33, -1\n\t"
            "v_mov_b32 v34, -1\n\t" "v_mov_b32 v35, -1\n\t"
            "v_mov_b32 v36, -1\n\t" "v_mov_b32 v37, -1\n\t"
            "v_mov_b32 v38, -1\n\t" "v_mov_b32 v39, -1\n\t"
            "v_mov_b32 v40, -1\n\t" "v_mov_b32 v41, -1\n\t"
            "v_mov_b32 v42, -1\n\t" "v_mov_b32 v43, -1\n\t"
            "v_mov_b32 v44, -1\n\t" "v_mov_b32 v45, -1\n\t"
            "v_mov_b32 v46, -1\n\t" "v_mov_b32 v47, -1\n\t"
            // preload pair 0 into fbA
            "ds_read_b128 v[48:51], v68 offset:0\n\t"
            "ds_read_b128 v[52:55], v68 offset:1024\n\t"
            PAIR_A("2048",  "3072")     // pair 0  (prefetch pair 1)
            PAIR_B("4096",  "5120")     // pair 1  (prefetch pair 2)
            PAIR_A("6144",  "7168")
            PAIR_B("8192",  "9216")
            PAIR_A("10240", "11264")
            PAIR_B("12288", "13312")
            PAIR_A("14336", "15360")
            PAIR_B("16384", "17408")
            PAIR_A("18432", "19456")
            PAIR_B("20480", "21504")
            PAIR_A("22528", "23552")
            PAIR_B("24576", "25600")
            PAIR_A("26624", "27648")
            PAIR_B("28672", "29696")
            PAIR_A("30720", "31744")    // pair 14 (prefetch pair 15)
            PAIR_B_LAST                 // pair 15
            "v_mov_b32 %0, v32\n\t"  "v_mov_b32 %1, v33\n\t"
            "v_mov_b32 %2, v34\n\t"  "v_mov_b32 %3, v35\n\t"
            "v_mov_b32 %4, v36\n\t"  "v_mov_b32 %5, v37\n\t"
            "v_mov_b32 %6, v38\n\t"  "v_mov_b32 %7, v39\n\t"
            "v_mov_b32 %8, v40\n\t"  "v_mov_b32 %9, v41\n\t"
            "v_mov_b32 %10, v42\n\t" "v_mov_b32 %11, v43\n\t"
            "v_mov_b32 %12, v44\n\t" "v_mov_b32 %13, v45\n\t"
            "v_mov_b32 %14, v46\n\t" "v_mov_b32 %15, v47"
            : "=v"(b0), "=v"(b1), "=v"(b2), "=v"(b3),
              "=v"(b4), "=v"(b5), "=v"(b6), "=v"(b7),
              "=v"(b8), "=v"(b9), "=v"(b10), "=v"(b11),
              "=v"(b12), "=v"(b13), "=v"(b14), "=v"(b15)
            : [fa]"v"(a.s), [fz]"v"(zero), [m]"s"(mask),
              [vfb]"v"(vf_base), [lb]"v"(lds_base)
            : "v0","v1","v2","v3","v4","v5","v6","v7",
              "v8","v9","v10","v11","v12","v13","v14","v15",
              "v16","v17","v18","v19","v20","v21","v22","v23",
              "v24","v25","v26","v27","v28","v29","v30","v31",
              "v32","v33","v34","v35","v36","v37","v38","v39",
              "v40","v41","v42","v43","v44","v45","v46","v47",
              "v48","v49","v50","v51","v52","v53","v54","v55",
              "v56","v57","v58","v59","v60","v61","v62","v63",
              "v64","v65","v66","v67","v68","memory");

        unsigned best[16] = {b0, b1, b2, b3, b4, b5, b6, b7,
                             b8, b9, b10, b11, b12, b13, b14, b15};

        // min across the 32 face-columns (stays within each 32-lane half)
#pragma unroll
        for (int e = 0; e < 16; ++e) {
            unsigned v = best[e];
#pragma unroll
            for (int m = 1; m < 32; m <<= 1)
                v = min(v, (unsigned)__shfl_xor((int)v, m, 64));
            best[e] = v;
        }
        if ((lane & 31) == 0) {
            int half = lane >> 5;
#pragma unroll
            for (int r = 0; r < 16; ++r) {
                int row = (r & 3) + 8 * (r >> 2) + 4 * half;
                atomicMin(&kb[pt_tile * 32 + row], best[r]);
            }
        }
    }
}

// ---------------------------------------------------------------------------
// Per-point signed plane distance -> interp^3 sum + hit count; the LAST of
// the 128 blocks (device ticket) writes d_out. Fence cost is trivial here.
// ---------------------------------------------------------------------------
__global__ __launch_bounds__(TPB) void finalize_kernel(
        const float* __restrict__ pred,
        const float4* __restrict__ centers4,
        const float4* __restrict__ normals4,
        const unsigned int* __restrict__ keys,
        float* __restrict__ acc,
        unsigned* __restrict__ tk,
        float* __restrict__ out,
        int nblocks) {
    int i = blockIdx.x * blockDim.x + threadIdx.x;   // 0 .. B*N-1
    float val = 0.0f, cnt = 0.0f;
    if (i < NB * NP) {
        int b = i / NP;
        unsigned key = keys[i];
        int idx = (int)(key & (unsigned)(NF - 1));
        float4 c  = centers4[b * NF + idx];
        float4 nr = normals4[b * NF + idx];
        const float* pp = pred + (size_t)i * 3;
        float dx = pp[0] - c.x, dy = pp[1] - c.y, dz = pp[2] - c.z;
        float dist = dx * nr.x + dy * nr.y + dz * nr.z;
        float t = F_EPS - dist;
        if (t > 0.0f) { cnt = 1.0f; val = t * t * t; }
    }
    for (int off = 32; off > 0; off >>= 1) {
        val += __shfl_down(val, off, 64);
        cnt += __shfl_down(cnt, off, 64);
    }
    __shared__ float sv[TPB / 64], sn[TPB / 64];
    __shared__ unsigned s_tkt;
    int lane = threadIdx.x & 63, wave = threadIdx.x >> 6;
    if (lane == 0) { sv[wave] = val; sn[wave] = cnt; }
    __syncthreads();
    if (threadIdx.x == 0) {
        float v = 0.0f, cc = 0.0f;
#pragma unroll
        for (int w = 0; w < TPB / 64; ++w) { v += sv[w]; cc += sn[w]; }
        atomicAdd(&acc[0], v);
        atomicAdd(&acc[1], cc);
        __threadfence();
        s_tkt = atomicAdd(&tk[0], 1u);
        if (s_tkt == (unsigned)(nblocks - 1)) {      // last block writes out
            float a0 = __hip_atomic_load(&acc[0], __ATOMIC_RELAXED, __HIP_MEMORY_SCOPE_AGENT);
            float a1 = __hip_atomic_load(&acc[1], __ATOMIC_RELAXED, __HIP_MEMORY_SCOPE_AGENT);
            out[0] = a0 * (F_WEIGHT / (float)NB);
            out[1] = a1 * (1.0f / (float)(NB * NP));
        }
    }
}

extern "C" void kernel_launch(void* const* d_in, const int* in_sizes, int n_in,
                              void* d_out, int out_size, void* d_ws, size_t ws_size,
                              hipStream_t stream) {
    const float* pred  = (const float*)d_in[0];   // [B,N,3] f32
    const float* opos  = (const float*)d_in[1];   // [B,V,3] f32
    const int*   faces = (const int*)  d_in[2];   // [B,F,3] i32

    char* ws = (char*)d_ws;
    const size_t a_bytes = (size_t)NB * PT_TILES * 64 * 16;   // 1 MiB
    const size_t b_bytes = (size_t)NB * FC_TILES * 64 * 16;   // 2 MiB
    const size_t c_bytes = (size_t)NB * NF * 16;              // 1 MiB
    const size_t k_bytes = (size_t)NB * NP * sizeof(unsigned);// 128 KiB

    uint4*    a_frags  = (uint4*)ws;
    uint4*    b_frags  = (uint4*)(ws + a_bytes);
    float4*   centers4 = (float4*)(ws + a_bytes + b_bytes);
    float4*   normals4 = (float4*)(ws + a_bytes + b_bytes + c_bytes);
    unsigned* keys     = (unsigned*)(ws + a_bytes + b_bytes + 2 * c_bytes);
    float*    acc      = (float*)(ws + a_bytes + b_bytes + 2 * c_bytes + k_bytes);
    unsigned* tk       = (unsigned*)(ws + a_bytes + b_bytes + 2 * c_bytes + k_bytes + 64);

    prep_kernel<<<(NB * NF + TPB - 1) / TPB, TPB, 0, stream>>>(
        pred, opos, faces, a_frags, b_frags, centers4, normals4, keys, acc, tk);

    nn_kernel<<<dim3(PGB, FS, NB), TPB, 0, stream>>>(a_frags, b_frags, keys);

    int fin_blocks = (NB * NP + TPB - 1) / TPB;
    finalize_kernel<<<fin_blocks, TPB, 0, stream>>>(
        pred, centers4, normals4, keys, acc, tk, (float*)d_out, fin_blocks);
}

// Round 17
// 104.532 us; speedup vs baseline: 1.0600x; 1.0600x over previous
//
#include <hip/hip_runtime.h>
#include <cstdint>

typedef __attribute__((ext_vector_type(8)))  short short8;
typedef __attribute__((ext_vector_type(16))) float floatx16;

constexpr int NB = 4;        // batch
constexpr int NV = 8192;     // vertices
constexpr int NF = 16384;    // faces
constexpr int NP = 8192;     // query points per batch
constexpr float F_EPS = 1e-3f;
constexpr float F_WEIGHT = 1000.0f;
constexpr float BIAS = 1e-3f;        // keeps dist^2 > 0 despite bf16 rounding

constexpr int PT_TILES = NP / 32;        // 256 point tiles (32-wide) / batch
constexpr int FC_TILES = NF / 32;        // 512 face tiles (32-wide) / batch
constexpr int TPB = 256;                 // 4 waves
constexpr int FS = 16;                   // face slices
constexpr int SL_TILES = FC_TILES / FS;  // 32 face tiles (1024 faces) / slice -> 32KB LDS
constexpr int GPW = 2;                   // A-pair iterations per wave (2 tiles each)
constexpr int PGB = 16;                  // point groups (512 pts) / batch
// grid = PGB x FS x NB = 1024 blocks = 4/CU, co-resident

union FragU { uint4 u; short8 s; };

__device__ inline unsigned f2bf(float f) {           // fp32 -> bf16 (RNE)
    unsigned u = __float_as_uint(f);
    return (u + 0x7FFFu + ((u >> 16) & 1u)) >> 16;
}
__device__ inline float bf2f(unsigned h) { return __uint_as_float(h << 16); }
__device__ inline unsigned pk(unsigned lo, unsigned hi) {
    return (lo & 0xFFFFu) | (hi << 16);
}

// ---------------------------------------------------------------------------
// Fused prep (frag packing verified absmax 0.0 r6-r16). keys init removed:
// per-slice skeys are fully overwritten by nn (no atomics, no init needed).
// ---------------------------------------------------------------------------
__global__ void prep_kernel(const float* __restrict__ pred,
                            const float* __restrict__ pos,
                            const int*   __restrict__ faces,
                            uint4* __restrict__ a_frags,
                            uint4* __restrict__ b_frags,
                            float4* __restrict__ centers4,
                            float4* __restrict__ normals4,
                            float* __restrict__ acc,
                            unsigned* __restrict__ tk) {
    int i = blockIdx.x * blockDim.x + threadIdx.x;   // [0, NB*NF)
    if (i >= NB * NF) return;
    if (i < 2) acc[i] = 0.0f;
    if (i == 0) tk[0] = 0u;

    const unsigned ONE = 0x3F80u;

    // ---- faces ----
    {
        int b = i / NF, f = i & (NF - 1);
        const float* p = pos + (size_t)b * NV * 3;
        int i0 = faces[3 * (size_t)i], i1 = faces[3 * (size_t)i + 1], i2 = faces[3 * (size_t)i + 2];
        float ax = p[3 * i0], ay = p[3 * i0 + 1], az = p[3 * i0 + 2];
        float bx = p[3 * i1], by = p[3 * i1 + 1], bz = p[3 * i1 + 2];
        float cx = p[3 * i2], cy = p[3 * i2 + 1], cz = p[3 * i2 + 2];

        const float third = 1.0f / 3.0f;
        float mx = (ax + bx + cx) * third;
        float my = (ay + by + cy) * third;
        float mz = (az + bz + cz) * third;
        float c2 = mx * mx + my * my + mz * mz;

        float e1x = bx - ax, e1y = by - ay, e1z = bz - az;
        float e2x = cx - ax, e2y = cy - ay, e2z = cz - az;
        float nx = e1y * e2z - e1z * e2y;
        float ny = e1z * e2x - e1x * e2z;
        float nz = e1x * e2y - e1y * e2x;
        float len = sqrtf(nx * nx + ny * ny + nz * nz);
        float inv = 1.0f / fmaxf(len, 1e-12f);

        centers4[i] = make_float4(mx, my, mz, c2);
        normals4[i] = make_float4(nx * inv, ny * inv, nz * inv, 0.0f);

        unsigned bhx = f2bf(mx), bhy = f2bf(my), bhz = f2bf(mz);
        unsigned blx = f2bf(mx - bf2f(bhx)), bly = f2bf(my - bf2f(bhy)), blz = f2bf(mz - bf2f(bhz));
        unsigned c2h = f2bf(c2);
        unsigned c2l = f2bf(c2 - bf2f(c2h));

        int tile = f >> 5, n = f & 31;
        uint4* bb = b_frags + (size_t)(b * FC_TILES + tile) * 64;
        bb[n]      = make_uint4(pk(bhx, bhy), pk(bhz, bhx), pk(bhy, bhz), pk(blx, bly)); // k0..7
        bb[32 + n] = make_uint4(pk(blz, blx), pk(bly, blz), pk(c2h, c2l), pk(ONE, ONE)); // k8..15
    }

    // ---- points ----
    if (i < NB * NP) {
        int pb = i / NP, pn = i & (NP - 1);
        float x = pred[3 * (size_t)i], y = pred[3 * (size_t)i + 1], z = pred[3 * (size_t)i + 2];
        unsigned hx = f2bf(x), hy = f2bf(y), hz = f2bf(z);
        float rx = x - bf2f(hx), ry = y - bf2f(hy), rz = z - bf2f(hz);
        unsigned ahx = f2bf(-2.f * bf2f(hx)), ahy = f2bf(-2.f * bf2f(hy)), ahz = f2bf(-2.f * bf2f(hz));
        unsigned alx = f2bf(-2.f * rx), aly = f2bf(-2.f * ry), alz = f2bf(-2.f * rz);
        float p2 = x * x + y * y + z * z + BIAS;
        unsigned p2h = f2bf(p2);
        unsigned p2l = f2bf(p2 - bf2f(p2h));

        int tile = pn >> 5, m = pn & 31;
        uint4* ab = a_frags + (size_t)(pb * PT_TILES + tile) * 64;
        ab[m]      = make_uint4(pk(ahx, ahy), pk(ahz, alx), pk(aly, alz), pk(ahx, ahy)); // k0..7
        ab[32 + m] = make_uint4(pk(ahz, alx), pk(aly, alz), pk(ONE, ONE), pk(p2h, p2l)); // k8..15
    }
}

// Epilogue triple: k0=(D0&mask)|vf ; k1=(D1&mask)|vf32 ; best=min3(best,k0,k1)
#define EP(D0, D1, BB) \
    "v_and_or_b32 v80, " D0 ", %[m], v82\n\t" \
    "v_and_or_b32 v81, " D1 ", %[m], v83\n\t" \
    "v_min3_u32 " BB ", " BB ", v80, v81\n\t"

#define EP0_ALL \
    EP("v0","v16","v32") EP("v1","v17","v33") EP("v2","v18","v34") EP("v3","v19","v35") \
    EP("v4","v20","v36") EP("v5","v21","v37") EP("v6","v22","v38") EP("v7","v23","v39") \
    EP("v8","v24","v40") EP("v9","v25","v41") EP("v10","v26","v42") EP("v11","v27","v43") \
    EP("v12","v28","v44") EP("v13","v29","v45") EP("v14","v30","v46") EP("v15","v31","v47")

#define EP1_ALL \
    EP("v0","v16","v48") EP("v1","v17","v49") EP("v2","v18","v50") EP("v3","v19","v51") \
    EP("v4","v20","v52") EP("v5","v21","v53") EP("v6","v22","v54") EP("v7","v23","v55") \
    EP("v8","v24","v56") EP("v9","v25","v57") EP("v10","v26","v58") EP("v11","v27","v59") \
    EP("v12","v28","v60") EP("v13","v29","v61") EP("v14","v30","v62") EP("v15","v31","v63")

// Both MFMA phases over one B-tile pair: phase0 = a0, phase1 = a1 (d banks reused).
#define BODY_X \
    "s_waitcnt lgkmcnt(2)\n\t" \
    "v_mfma_f32_32x32x16_bf16 v[0:15], %[fa0], v[64:67], %[fz]\n\t" \
    "v_mfma_f32_32x32x16_bf16 v[16:31], %[fa0], v[68:71], %[fz]\n\t" \
    "v_add_u32 v83, 32, v82\n\t" \
    "s_nop 7\n\t" "s_nop 7\n\t" "s_nop 7\n\t" \
    EP0_ALL \
    "v_mfma_f32_32x32x16_bf16 v[0:15], %[fa1], v[64:67], %[fz]\n\t" \
    "v_mfma_f32_32x32x16_bf16 v[16:31], %[fa1], v[68:71], %[fz]\n\t" \
    "s_nop 7\n\t" "s_nop 7\n\t" "s_nop 7\n\t" \
    EP1_ALL \
    "v_add_u32 v82, 64, v82\n\t"

#define BODY_Y \
    "s_waitcnt lgkmcnt(2)\n\t" \
    "v_mfma_f32_32x32x16_bf16 v[0:15], %[fa0], v[72:75], %[fz]\n\t" \
    "v_mfma_f32_32x32x16_bf16 v[16:31], %[fa0], v[76:79], %[fz]\n\t" \
    "v_add_u32 v83, 32, v82\n\t" \
    "s_nop 7\n\t" "s_nop 7\n\t" "s_nop 7\n\t" \
    EP0_ALL \
    "v_mfma_f32_32x32x16_bf16 v[0:15], %[fa1], v[72:75], %[fz]\n\t" \
    "v_mfma_f32_32x32x16_bf16 v[16:31], %[fa1], v[76:79], %[fz]\n\t" \
    "s_nop 7\n\t" "s_nop 7\n\t" "s_nop 7\n\t" \
    EP1_ALL \
    "v_add_u32 v82, 64, v82\n\t"

// Consume X (v64-71), prefetch next pair into Y (v72-79); and vice versa.
#define ITER_X(P0, P1) \
    "ds_read_b128 v[72:75], v84 offset:" P0 "\n\t" \
    "ds_read_b128 v[76:79], v84 offset:" P1 "\n\t" \
    BODY_X
#define ITER_Y(P0, P1) \
    "ds_read_b128 v[64:67], v84 offset:" P0 "\n\t" \
    "ds_read_b128 v[68:71], v84 offset:" P1 "\n\t" \
    BODY_Y
#define ITER_Y_LAST \
    "s_waitcnt lgkmcnt(1)\n\t" \
    "v_mfma_f32_32x32x16_bf16 v[0:15], %[fa0], v[72:75], %[fz]\n\t" \
    "s_waitcnt lgkmcnt(0)\n\t" \
    "v_mfma_f32_32x32x16_bf16 v[16:31], %[fa0], v[76:79], %[fz]\n\t" \
    "v_add_u32 v83, 32, v82\n\t" \
    "s_nop 7\n\t" "s_nop 7\n\t" "s_nop 7\n\t" \
    EP0_ALL \
    "v_mfma_f32_32x32x16_bf16 v[0:15], %[fa1], v[72:75], %[fz]\n\t" \
    "v_mfma_f32_32x32x16_bf16 v[16:31], %[fa1], v[76:79], %[fz]\n\t" \
    "s_nop 7\n\t" "s_nop 7\n\t" "s_nop 7\n\t" \
    EP1_ALL

// DPP in-row (16-lane) rotation min step for all 32 best regs
#define DPP1(R, S) "v_min_u32_dpp v" R ", v" R ", v" R " row_ror:" S " row_mask:0xf bank_mask:0xf\n\t"
#define DPPS(S) \
    DPP1("32",S) DPP1("33",S) DPP1("34",S) DPP1("35",S) DPP1("36",S) DPP1("37",S) \
    DPP1("38",S) DPP1("39",S) DPP1("40",S) DPP1("41",S) DPP1("42",S) DPP1("43",S) \
    DPP1("44",S) DPP1("45",S) DPP1("46",S) DPP1("47",S) DPP1("48",S) DPP1("49",S) \
    DPP1("50",S) DPP1("51",S) DPP1("52",S) DPP1("53",S) DPP1("54",S) DPP1("55",S) \
    DPP1("56",S) DPP1("57",S) DPP1("58",S) DPP1("59",S) DPP1("60",S) DPP1("61",S) \
    DPP1("62",S) DPP1("63",S)

#define SWZ(D, S) "ds_swizzle_b32 v" D ", v" S " offset:0x401F\n\t"
#define MN(A, B)  "v_min_u32 v" A ", v" A ", v" B "\n\t"
#define ST(R, OFF) "global_store_dword %[kb], v" R ", off offset:" OFF "\n\t"

// ---------------------------------------------------------------------------
// 1-NN: mega-asm with (1) A-tile pairing (2 ds_read per 4 MFMAs -- halves
// pair-loop LDS, the newly-identified dominant pipe: ~55k cyc/CU of DS in
// r15/r16 incl. the 80-swizzle shuffle tail), (2) DPP row_ror min-reduction
// (4 of 5 tail steps on VALU, only xor16 stays a swizzle), (3) per-slice
// plain stores instead of atomicMin (kills the 8MB WRITE_SIZE ping-pong;
// finalize mins the 16 slices). Reduction + stores live inside the asm.
// Register map: v0-31 d banks | v32-47 best0 | v48-63 best1 | v64-79 B bufs
// v80/81 k-scratch | v82 vf | v83 vf+32 | v84 LDS addr.
// C/D layout verified r4-r16: col=lane&31, row=(reg&3)+8*(reg>>2)+4*(lane>>5).
// key = (bits(dist^2+BIAS) & 0xFFFFC000) | face_idx.
// ---------------------------------------------------------------------------
__global__ __launch_bounds__(TPB) void nn_kernel(
        const uint4* __restrict__ a_frags,
        const uint4* __restrict__ b_frags,
        unsigned* __restrict__ skeys) {
    const int pg = blockIdx.x, sl = blockIdx.y, b = blockIdx.z;
    const int tid = threadIdx.x, wave = tid >> 6, lane = tid & 63;

    __shared__ uint4 sb[SL_TILES * 64];        // 32 KB

    // async DMA stage of the whole 32-tile slice
    const uint4* gsrc = b_frags + ((size_t)(b * FC_TILES + sl * SL_TILES)) * 64;
#pragma unroll
    for (int k = 0; k < (SL_TILES * 64) / TPB; ++k) {
        __builtin_amdgcn_global_load_lds(
            (const __attribute__((address_space(1))) unsigned int*)(const void*)(gsrc + k * TPB + tid),
            (__attribute__((address_space(3))) unsigned int*)(void*)&sb[k * TPB + (wave << 6)],
            16, 0, 0);
    }
    __syncthreads();

    const floatx16 zero = {0.f, 0.f, 0.f, 0.f, 0.f, 0.f, 0.f, 0.f,
                           0.f, 0.f, 0.f, 0.f, 0.f, 0.f, 0.f, 0.f};
    const unsigned mask = 0xFFFFC000u;
    const unsigned vf_base = (unsigned)(sl * (SL_TILES * 32) + (lane & 31));
    const unsigned lds_base = (unsigned)(unsigned long long)&sb[lane];
    const unsigned act = ((lane & 31) == 0) ? 1u : 0u;
    unsigned* skb = skeys + ((size_t)(b * FS + sl)) * NP;

#pragma unroll 1
    for (int g = 0; g < GPW; ++g) {
        const int pt0 = pg * 16 + g * 8 + wave * 2;   // this wave's A-tile pair
        FragU a0, a1;
        a0.u = a_frags[((size_t)(b * PT_TILES + pt0)) * 64 + lane];
        a1.u = a_frags[((size_t)(b * PT_TILES + pt0 + 1)) * 64 + lane];
        unsigned long long kaddr =
            (unsigned long long)(skb + pt0 * 32 + ((lane >> 5) * 4));
        unsigned long long saved;

        asm volatile(
            "v_mov_b32 v84, %[lb]\n\t"
            "v_mov_b32 v82, %[vfb]\n\t"
            "v_mov_b32 v32, -1\n\t" "v_mov_b32 v33, -1\n\t"
            "v_mov_b32 v34, -1\n\t" "v_mov_b32 v35, -1\n\t"
            "v_mov_b32 v36, -1\n\t" "v_mov_b32 v37, -1\n\t"
            "v_mov_b32 v38, -1\n\t" "v_mov_b32 v39, -1\n\t"
            "v_mov_b32 v40, -1\n\t" "v_mov_b32 v41, -1\n\t"
            "v_mov_b32 v42, -1\n\t" "v_mov_b32 v43, -1\n\t"
            "v_mov_b32 v44, -1\n\t" "v_mov_b32 v45, -1\n\t"
            "v_mov_b32 v46, -1\n\t" "v_mov_b32 v47, -1\n\t"
            "v_mov_b32 v48, -1\n\t" "v_mov_b32 v49, -1\n\t"
            "v_mov_b32 v50, -1\n\t" "v_mov_b32 v51, -1\n\t"
            "v_mov_b32 v52, -1\n\t" "v_mov_b32 v53, -1\n\t"
            "v_mov_b32 v54, -1\n\t" "v_mov_b32 v55, -1\n\t"
            "v_mov_b32 v56, -1\n\t" "v_mov_b32 v57, -1\n\t"
            "v_mov_b32 v58, -1\n\t" "v_mov_b32 v59, -1\n\t"
            "v_mov_b32 v60, -1\n\t" "v_mov_b32 v61, -1\n\t"
            "v_mov_b32 v62, -1\n\t" "v_mov_b32 v63, -1\n\t"
            // preload pair 0 into X
            "ds_read_b128 v[64:67], v84 offset:0\n\t"
            "ds_read_b128 v[68:71], v84 offset:1024\n\t"
            ITER_X("2048",  "3072")
            ITER_Y("4096",  "5120")
            ITER_X("6144",  "7168")
            ITER_Y("8192",  "9216")
            ITER_X("10240", "11264")
            ITER_Y("12288", "13312")
            ITER_X("14336", "15360")
            ITER_Y("16384", "17408")
            ITER_X("18432", "19456")
            ITER_Y("20480", "21504")
            ITER_X("22528", "23552")
            ITER_Y("24576", "25600")
            ITER_X("26624", "27648")
            ITER_Y("28672", "29696")
            ITER_X("30720", "31744")
            ITER_Y_LAST
            // ---- column reduction: 4 DPP row_ror steps (16-lane rows) ----
            "s_nop 1\n\t"
            DPPS("1") DPPS("2") DPPS("4") DPPS("8")
            // ---- cross-row (xor16) via one swizzle per reg ----
            SWZ("0","32") SWZ("1","33") SWZ("2","34") SWZ("3","35")
            SWZ("4","36") SWZ("5","37") SWZ("6","38") SWZ("7","39")
            SWZ("8","40") SWZ("9","41") SWZ("10","42") SWZ("11","43")
            SWZ("12","44") SWZ("13","45") SWZ("14","46") SWZ("15","47")
            SWZ("16","48") SWZ("17","49") SWZ("18","50") SWZ("19","51")
            SWZ("20","52") SWZ("21","53") SWZ("22","54") SWZ("23","55")
            SWZ("24","56") SWZ("25","57") SWZ("26","58") SWZ("27","59")
            SWZ("28","60") SWZ("29","61") SWZ("30","62") SWZ("31","63")
            "s_waitcnt lgkmcnt(0)\n\t"
            MN("32","0") MN("33","1") MN("34","2") MN("35","3")
            MN("36","4") MN("37","5") MN("38","6") MN("39","7")
            MN("40","8") MN("41","9") MN("42","10") MN("43","11")
            MN("44","12") MN("45","13") MN("46","14") MN("47","15")
            MN("48","16") MN("49","17") MN("50","18") MN("51","19")
            MN("52","20") MN("53","21") MN("54","22") MN("55","23")
            MN("56","24") MN("57","25") MN("58","26") MN("59","27")
            MN("60","28") MN("61","29") MN("62","30") MN("63","31")
            // ---- stores from lanes 0 and 32 only ----
            "v_cmp_eq_u32 vcc, 1, %[act]\n\t"
            "s_and_saveexec_b64 %[sv], vcc\n\t"
            ST("32","0")   ST("33","4")   ST("34","8")   ST("35","12")
            ST("36","32")  ST("37","36")  ST("38","40")  ST("39","44")
            ST("40","64")  ST("41","68")  ST("42","72")  ST("43","76")
            ST("44","96")  ST("45","100") ST("46","104") ST("47","108")
            ST("48","128") ST("49","132") ST("50","136") ST("51","140")
            ST("52","160") ST("53","164") ST("54","168") ST("55","172")
            ST("56","192") ST("57","196") ST("58","200") ST("59","204")
            ST("60","224") ST("61","228") ST("62","232") ST("63","236")
            "s_mov_b64 exec, %[sv]"
            : [sv]"=&s"(saved)
            : [fa0]"v"(a0.s), [fa1]"v"(a1.s), [fz]"v"(zero), [m]"s"(mask),
              [vfb]"v"(vf_base), [lb]"v"(lds_base), [act]"v"(act),
              [kb]"v"(kaddr)
            : "v0","v1","v2","v3","v4","v5","v6","v7",
              "v8","v9","v10","v11","v12","v13","v14","v15",
              "v16","v17","v18","v19","v20","v21","v22","v23",
              "v24","v25","v26","v27","v28","v29","v30","v31",
              "v32","v33","v34","v35","v36","v37","v38","v39",
              "v40","v41","v42","v43","v44","v45","v46","v47",
              "v48","v49","v50","v51","v52","v53","v54","v55",
              "v56","v57","v58","v59","v60","v61","v62","v63",
              "v64","v65","v66","v67","v68","v69","v70","v71",
              "v72","v73","v74","v75","v76","v77","v78","v79",
              "v80","v81","v82","v83","v84","vcc","scc","memory");
    }
}

// ---------------------------------------------------------------------------
// Finalize: min over the 16 slice keys, then signed plane distance ->
// interp^3 sum + hit count; last block (ticket) writes d_out.
// ---------------------------------------------------------------------------
__global__ __launch_bounds__(TPB) void finalize_kernel(
        const float* __restrict__ pred,
        const float4* __restrict__ centers4,
        const float4* __restrict__ normals4,
        const unsigned* __restrict__ skeys,
        float* __restrict__ acc,
        unsigned* __restrict__ tk,
        float* __restrict__ out,
        int nblocks) {
    int i = blockIdx.x * blockDim.x + threadIdx.x;   // 0 .. B*N-1
    float val = 0.0f, cnt = 0.0f;
    if (i < NB * NP) {
        int b = i / NP, n = i & (NP - 1);
        unsigned key = 0xFFFFFFFFu;
#pragma unroll
        for (int s = 0; s < FS; ++s)
            key = min(key, skeys[((size_t)(b * FS + s)) * NP + n]);
        int idx = (int)(key & (unsigned)(NF - 1));
        float4 c  = centers4[b * NF + idx];
        float4 nr = normals4[b * NF + idx];
        const float* pp = pred + (size_t)i * 3;
        float dx = pp[0] - c.x, dy = pp[1] - c.y, dz = pp[2] - c.z;
        float dist = dx * nr.x + dy * nr.y + dz * nr.z;
        float t = F_EPS - dist;
        if (t > 0.0f) { cnt = 1.0f; val = t * t * t; }
    }
    for (int off = 32; off > 0; off >>= 1) {
        val += __shfl_down(val, off, 64);
        cnt += __shfl_down(cnt, off, 64);
    }
    __shared__ float sv[TPB / 64], sn[TPB / 64];
    __shared__ unsigned s_tkt;
    int lane = threadIdx.x & 63, wave = threadIdx.x >> 6;
    if (lane == 0) { sv[wave] = val; sn[wave] = cnt; }
    __syncthreads();
    if (threadIdx.x == 0) {
        float v = 0.0f, cc = 0.0f;
#pragma unroll
        for (int w = 0; w < TPB / 64; ++w) { v += sv[w]; cc += sn[w]; }
        atomicAdd(&acc[0], v);
        atomicAdd(&acc[1], cc);
        __threadfence();
        s_tkt = atomicAdd(&tk[0], 1u);
        if (s_tkt == (unsigned)(nblocks - 1)) {      // last block writes out
            float a0 = __hip_atomic_load(&acc[0], __ATOMIC_RELAXED, __HIP_MEMORY_SCOPE_AGENT);
            float a1 = __hip_atomic_load(&acc[1], __ATOMIC_RELAXED, __HIP_MEMORY_SCOPE_AGENT);
            out[0] = a0 * (F_WEIGHT / (float)NB);
            out[1] = a1 * (1.0f / (float)(NB * NP));
        }
    }
}

extern "C" void kernel_launch(void* const* d_in, const int* in_sizes, int n_in,
                              void* d_out, int out_size, void* d_ws, size_t ws_size,
                              hipStream_t stream) {
    const float* pred  = (const float*)d_in[0];   // [B,N,3] f32
    const float* opos  = (const float*)d_in[1];   // [B,V,3] f32
    const int*   faces = (const int*)  d_in[2];   // [B,F,3] i32

    char* ws = (char*)d_ws;
    const size_t a_bytes = (size_t)NB * PT_TILES * 64 * 16;   // 1 MiB
    const size_t b_bytes = (size_t)NB * FC_TILES * 64 * 16;   // 2 MiB
    const size_t c_bytes = (size_t)NB * NF * 16;              // 1 MiB
    const size_t s_bytes = (size_t)NB * FS * NP * 4;          // 2 MiB

    uint4*    a_frags  = (uint4*)ws;
    uint4*    b_frags  = (uint4*)(ws + a_bytes);
    float4*   centers4 = (float4*)(ws + a_bytes + b_bytes);
    float4*   normals4 = (float4*)(ws + a_bytes + b_bytes + c_bytes);
    unsigned* skeys    = (unsigned*)(ws + a_bytes + b_bytes + 2 * c_bytes);
    float*    acc      = (float*)(ws + a_bytes + b_bytes + 2 * c_bytes + s_bytes);
    unsigned* tk       = (unsigned*)(ws + a_bytes + b_bytes + 2 * c_bytes + s_bytes + 64);

    prep_kernel<<<(NB * NF + TPB - 1) / TPB, TPB, 0, stream>>>(
        pred, opos, faces, a_frags, b_frags, centers4, normals4, acc, tk);

    nn_kernel<<<dim3(PGB, FS, NB), TPB, 0, stream>>>(a_frags, b_frags, skeys);

    int fin_blocks = (NB * NP + TPB - 1) / TPB;
    finalize_kernel<<<fin_blocks, TPB, 0, stream>>>(
        pred, centers4, normals4, skeys, acc, tk, (float*)d_out, fin_blocks);
}